// Round 4
// baseline (638.742 us; speedup 1.0000x reference)
//
#include <hip/hip_runtime.h>
#include <cstddef>

#define BB   16384
#define TT_  100
#define FF   64
#define K4   20
#define NOUT 3

typedef float ZBUF[8][K4][9];
typedef float HIST[8][64];

__device__ __forceinline__ float sigf(float x) {
    return __builtin_amdgcn_rcpf(1.0f + __expf(-x));
}
__device__ __forceinline__ float tanhf_fast(float x) {
    return 1.0f - 2.0f * __builtin_amdgcn_rcpf(__expf(2.0f * x) + 1.0f);
}
template <int IMM>
__device__ __forceinline__ float swz(float v) {
    return __int_as_float(__builtin_amdgcn_ds_swizzle(__float_as_int(v), IMM));
}
__device__ __forceinline__ void lstm_act(const float (&z)[4], float& c, float& ho) {
    const float iv = sigf(z[0]), fv = sigf(z[1]);
    const float gv = tanhf_fast(z[2]), ov = sigf(z[3]);
    c = fmaf(fv, c, iv * gv);
    ho = ov * tanhf_fast(c);
}

// One pipeline step at slot s: L1 does time 8p+s, L2 8(p-1)+s, L3 8(p-2)+s.
// The three layer bodies are mutually independent -> 3 interleavable chains.
// h handoff between layers goes through LDS history (written one phase ago,
// so no latency coupling).  Hist reads at top, writes at bottom (same-wave DS
// ops are in-order -> WAR on slot s is safe without barriers).
template <bool D1, bool D2, bool D3>
__device__ __forceinline__ void pipe_step(
    int s, ZBUF& zbuf, HIST& h1hist, HIST& h2hist,
    int g, int ue, int lane,
    const float (&u1w)[4][5], const float (&w2w)[4][5], const float (&u2w)[4][5],
    const float (&w3w)[4][5], const float (&u3w)[4][5],
    const float (&bb1)[4], const float (&bb2)[4], const float (&bb3)[4],
    float (&h1)[5], float (&h2)[5], float (&h3)[5],
    float& c1, float& c2, float& c3)
{
    float nh1[5], nh2[5];
    if (D2) {
#pragma unroll
        for (int d = 0; d < 5; ++d) nh1[d] = h1hist[s][g * 8 + d];
    }
    if (D3) {
#pragma unroll
        for (int d = 0; d < 5; ++d) nh2[d] = h2hist[s][g * 8 + d];
    }

    float ho1, ho2, ho3;
    if (D1) {
        float z[4];
#pragma unroll
        for (int j = 0; j < 4; ++j) {
            float acc = zbuf[s][j * 5 + ue][g] + bb1[j];
#pragma unroll
            for (int d = 0; d < 5; ++d) acc = fmaf(h1[d], u1w[j][d], acc);
            z[j] = acc;
        }
        lstm_act(z, c1, ho1);
    }
    if (D2) {
        float z[4];
#pragma unroll
        for (int j = 0; j < 4; ++j) {
            float acc = bb2[j];
#pragma unroll
            for (int d = 0; d < 5; ++d) acc = fmaf(nh1[d], w2w[j][d], acc);
#pragma unroll
            for (int d = 0; d < 5; ++d) acc = fmaf(h2[d], u2w[j][d], acc);
            z[j] = acc;
        }
        lstm_act(z, c2, ho2);
    }
    if (D3) {
        float z[4];
#pragma unroll
        for (int j = 0; j < 4; ++j) {
            float acc = bb3[j];
#pragma unroll
            for (int d = 0; d < 5; ++d) acc = fmaf(nh2[d], w3w[j][d], acc);
#pragma unroll
            for (int d = 0; d < 5; ++d) acc = fmaf(h3[d], u3w[j][d], acc);
            z[j] = acc;
        }
        lstm_act(z, c3, ho3);
    }

    if (D1) {
        h1hist[s][lane] = ho1;
        h1[0] = swz<0x018>(ho1); h1[1] = swz<0x038>(ho1);
        h1[2] = swz<0x058>(ho1); h1[3] = swz<0x078>(ho1);
        h1[4] = swz<0x098>(ho1);
    }
    if (D2) {
        h2hist[s][lane] = ho2;
        h2[0] = swz<0x018>(ho2); h2[1] = swz<0x038>(ho2);
        h2[2] = swz<0x058>(ho2); h2[3] = swz<0x078>(ho2);
        h2[4] = swz<0x098>(ho2);
    }
    if (D3) {
        h3[0] = swz<0x018>(ho3); h3[1] = swz<0x038>(ho3);
        h3[2] = swz<0x058>(ho3); h3[3] = swz<0x078>(ho3);
        h3[4] = swz<0x098>(ho3);
    }
}

// Projection of one 8-t chunk: lane role (g,tq,fh); k-outer reads each W1
// float4 once (wave-uniform 2-addr LDS broadcast, free) feeding 8 FMAs.
__device__ __forceinline__ void proj_chunk(
    const float (&sWT)[K4][FF], ZBUF& zbuf,
    const float4 (&xa0)[8], const float4 (&xa1)[8],
    int fh, int t1, int g)
{
#pragma unroll 4
    for (int k = 0; k < K4; ++k) {
        float a0 = 0.f, a1 = 0.f;
#pragma unroll
        for (int fc = 0; fc < 8; ++fc) {
            const float4 wv = *(const float4*)&sWT[k][fh * 32 + fc * 4];
            const float4 x0 = xa0[fc];
            const float4 x1 = xa1[fc];
            a0 = fmaf(x0.x, wv.x, fmaf(x0.y, wv.y, fmaf(x0.z, wv.z, fmaf(x0.w, wv.w, a0))));
            a1 = fmaf(x1.x, wv.x, fmaf(x1.y, wv.y, fmaf(x1.z, wv.z, fmaf(x1.w, wv.w, a1))));
        }
        a0 += swz<0x041F>(a0);   // combine f-halves
        a1 += swz<0x041F>(a1);
        zbuf[t1][k][g] = fh ? a1 : a0;
    }
}

__device__ __forceinline__ void load_x(const float* p0, const float* p1,
                                       float4 (&xa0)[8], float4 (&xa1)[8])
{
#pragma unroll
    for (int fc = 0; fc < 8; ++fc) xa0[fc] = ((const float4*)p0)[fc];
#pragma unroll
    for (int fc = 0; fc < 8; ++fc) xa1[fc] = ((const float4*)p1)[fc];
}

// ---------------------------------------------------------------------------
// Fused x-proj + 3-layer LSTM + head, layer-wavefront-pipelined.
// One wave per 8 batch elements; lane u owns unit u's i/f/g/o (3 dup lanes).
// Phase p: proj(chunk p) ; L1 on chunk p, L2 on p-1, L3 on p-2.
// waves_per_eu(2,2): grid is exactly 2 waves/SIMD, so a 256-VGPR budget is
// free and prevents the round-2 spill catastrophe.
// ---------------------------------------------------------------------------
__global__ __launch_bounds__(64) __attribute__((amdgpu_waves_per_eu(2, 2)))
void fused_lstm_kernel(
    const float* __restrict__ x,
    const float* __restrict__ W1, const float* __restrict__ U1, const float* __restrict__ b1,
    const float* __restrict__ W2, const float* __restrict__ U2, const float* __restrict__ b2,
    const float* __restrict__ W3, const float* __restrict__ U3, const float* __restrict__ b3,
    const float* __restrict__ Wd, const float* __restrict__ bd,
    float* __restrict__ out)
{
    __shared__ float sWT[K4][FF];
    __shared__ ZBUF zbuf;
    __shared__ HIST h1hist;
    __shared__ HIST h2hist;

    const int lane = threadIdx.x;
    const int g    = lane >> 3;
    const int u    = lane & 7;
    const int ue   = (u < 5) ? u : 4;
    const int tq   = (lane >> 1) & 3;
    const int fh   = lane & 1;
    const int b    = blockIdx.x * 8 + g;
    const int t1   = tq + (fh << 2);

    // chunk-0 x loads first (hide HBM latency behind setup)
    const float* xp0 = x + ((size_t)b * TT_ + tq) * FF + fh * 32;
    const float* xp1 = xp0 + 4 * FF;
    float4 xa0[8], xa1[8];
    load_x(xp0, xp1, xa0, xa1);

#pragma unroll
    for (int w = 0; w < 20; ++w) {
        int i = w * 64 + lane;
        sWT[i % K4][i / K4] = W1[i];
    }

    float u1w[4][5], w2w[4][5], u2w[4][5], w3w[4][5], u3w[4][5];
    float bb1[4], bb2[4], bb3[4];
#pragma unroll
    for (int j = 0; j < 4; ++j) {
        const int k = j * 5 + ue;
#pragma unroll
        for (int d = 0; d < 5; ++d) {
            u1w[j][d] = U1[d * K4 + k];
            w2w[j][d] = W2[d * K4 + k];
            u2w[j][d] = U2[d * K4 + k];
            w3w[j][d] = W3[d * K4 + k];
            u3w[j][d] = U3[d * K4 + k];
        }
        bb1[j] = b1[k];
        bb2[j] = b2[k];
        bb3[j] = b3[k];
    }
    const int uo = (u < NOUT) ? u : 0;
    float wdw[5];
    const float bdw = bd[uo];
#pragma unroll
    for (int d = 0; d < 5; ++d) wdw[d] = Wd[d * NOUT + uo];

    float h1[5] = {0,0,0,0,0}, h2[5] = {0,0,0,0,0}, h3[5] = {0,0,0,0,0};
    float c1 = 0.f, c2 = 0.f, c3 = 0.f;

#define STEP(D1, D2, D3, S)                                                   \
    pipe_step<D1, D2, D3>(S, zbuf, h1hist, h2hist, g, ue, lane,               \
                          u1w, w2w, u2w, w3w, u3w, bb1, bb2, bb3,             \
                          h1, h2, h3, c1, c2, c3)

#define PREFETCH(p)                                                           \
    do {                                                                      \
        xp0 += 8 * FF;                                                        \
        xp1 = ((p) == 11) ? xp0 : (xp1 + 8 * FF); /* tail clamp */            \
        load_x(xp0, xp1, xa0, xa1);                                           \
    } while (0)

    // ---- phase 0: L1 only
    proj_chunk(sWT, zbuf, xa0, xa1, fh, t1, g);
    PREFETCH(0);
#pragma unroll
    for (int s = 0; s < 8; ++s) STEP(true, false, false, s);

    // ---- phase 1: L1+L2
    proj_chunk(sWT, zbuf, xa0, xa1, fh, t1, g);
    PREFETCH(1);
#pragma unroll
    for (int s = 0; s < 8; ++s) STEP(true, true, false, s);

    // ---- phases 2..11: steady state
#pragma unroll 1
    for (int p = 2; p < 12; ++p) {
        proj_chunk(sWT, zbuf, xa0, xa1, fh, t1, g);
        PREFETCH(p);
#pragma unroll
        for (int s = 0; s < 8; ++s) STEP(true, true, true, s);
    }

    // ---- phase 12: L1 tail (4 valid t), L2/L3 full
    proj_chunk(sWT, zbuf, xa0, xa1, fh, t1, g);
#pragma unroll
    for (int s = 0; s < 4; ++s) STEP(true, true, true, s);
#pragma unroll
    for (int s = 4; s < 8; ++s) STEP(false, true, true, s);

    // ---- phase 13: L2 tail, L3 full
#pragma unroll
    for (int s = 0; s < 4; ++s) STEP(false, true, true, s);
#pragma unroll
    for (int s = 4; s < 8; ++s) STEP(false, false, true, s);

    // ---- phase 14: L3 tail
#pragma unroll
    for (int s = 0; s < 4; ++s) STEP(false, false, true, s);

#undef STEP
#undef PREFETCH

    if (u < NOUT) {
        float sacc = bdw;
#pragma unroll
        for (int d = 0; d < 5; ++d) sacc = fmaf(h3[d], wdw[d], sacc);
        out[b * NOUT + u] = sacc;
    }
}

extern "C" void kernel_launch(void* const* d_in, const int* in_sizes, int n_in,
                              void* d_out, int out_size, void* d_ws, size_t ws_size,
                              hipStream_t stream) {
    const float* x   = (const float*)d_in[0];
    const float* W1  = (const float*)d_in[1];
    const float* U1  = (const float*)d_in[2];
    const float* b1  = (const float*)d_in[3];
    const float* W2  = (const float*)d_in[4];
    const float* U2  = (const float*)d_in[5];
    const float* b2  = (const float*)d_in[6];
    const float* W3  = (const float*)d_in[7];
    const float* U3  = (const float*)d_in[8];
    const float* b3  = (const float*)d_in[9];
    const float* Wd  = (const float*)d_in[10];
    const float* bdp = (const float*)d_in[11];
    float* out = (float*)d_out;

    fused_lstm_kernel<<<BB / 8, 64, 0, stream>>>(
        x, W1, U1, b1, W2, U2, b2, W3, U3, b3, Wd, bdp, out);
}